// Round 4
// baseline (566.735 us; speedup 1.0000x reference)
//
#include <hip/hip_runtime.h>
#include <cstdint>
#include <cstddef>

#define NN 8192
#define FIN 256
#define FOUT 128
#define SLOPE 0.2f
#define SHIFT 8.0f

typedef float f32x4 __attribute__((ext_vector_type(4)));
typedef __bf16 bf16x8 __attribute__((ext_vector_type(8)));
typedef unsigned int u32x4 __attribute__((ext_vector_type(4)));

__device__ __forceinline__ unsigned short f2bf(float f) {
  return __builtin_bit_cast(unsigned short, (__bf16)f);
}

// ---------------------------------------------------------------------------
// Kernel P: adj (256 MB int32 0/1) -> bitmask (8 MB). Pure HBM stream.
// Segment = 256 ints; lane L handles ints {L, L+64, L+128, L+192} -> 4 ballots
// give bits in exact j order. 8192 waves x 32 segments, fully coalesced.
// ---------------------------------------------------------------------------
__global__ __launch_bounds__(256) void k_pack(const int* __restrict__ adj,
                                              unsigned long long* __restrict__ mask) {
  const int wid = blockIdx.x * 4 + (threadIdx.x >> 6);   // 0..8191
  const int lane = threadIdx.x & 63;
  for (int s = wid; s < (NN * NN / 256); s += 8192) {
    const int* base = adj + (size_t)s * 256;
    int v0 = base[lane];
    int v1 = base[lane + 64];
    int v2 = base[lane + 128];
    int v3 = base[lane + 192];
    unsigned long long b0 = __ballot(v0 != 0);
    unsigned long long b1 = __ballot(v1 != 0);
    unsigned long long b2 = __ballot(v2 != 0);
    unsigned long long b3 = __ballot(v3 != 0);
    if (lane == 0) {
      unsigned long long* q = mask + (size_t)s * 4;
      q[0] = b0; q[1] = b1; q[2] = b2; q[3] = b3;
    }
  }
}

// ---------------------------------------------------------------------------
// Kernel A: h = x @ W (fp32 acc) -> ht[FOUT][NN] bf16 (transposed), plus fused
// s-reductions and the E/F exp-factor tables:
//   Etab[row] = (E, E2, Einv, 0) = (e^{s1-c}, e^{0.2 s1 - c}, e^{-s1}, 0),
//     c = leakyrelu(s1 + SHIFT)  (>= row max of leakyrelu(s1+s2))
//   Ftab[2j,2j+1] = (e^{s2}, e^{0.2 s2})
// so that exp(leakyrelu(s1+s2) - c) = (pos?E:E2)*(pos?F:F2), pos <=> F>=Einv.
// ht store goes through an LDS transpose -> 16B coalesced-ish stores.
// ---------------------------------------------------------------------------
__global__ __launch_bounds__(256, 4) void k_hw(const float* __restrict__ x,
                                               const float* __restrict__ W,
                                               const float* __restrict__ a1,
                                               const float* __restrict__ a2,
                                               unsigned short* __restrict__ ht,
                                               float* __restrict__ Etab,
                                               float* __restrict__ Ftab) {
  __shared__ float xs[8][256];
  __shared__ unsigned short tile[128][8];   // [f][row]
  const int tid = threadIdx.x;
  const int rowbase = blockIdx.x * 8;

  #pragma unroll
  for (int it = 0; it < 2; ++it) {
    int fi = it * 1024 + tid * 4;
    int r = fi >> 8, k = fi & 255;
    *(f32x4*)&xs[r][k] = *(const f32x4*)(x + (size_t)(rowbase + r) * FIN + k);
  }
  __syncthreads();

  const int r = tid >> 5;    // 0..7
  const int cg = tid & 31;   // cols cg*4..cg*4+3
  f32x4 acc = {0.f, 0.f, 0.f, 0.f};

  #pragma unroll 8
  for (int k = 0; k < FIN; ++k) {
    f32x4 wv = *(const f32x4*)(W + k * FOUT + cg * 4);
    float xv = xs[r][k];
    acc[0] += xv * wv[0];
    acc[1] += xv * wv[1];
    acc[2] += xv * wv[2];
    acc[3] += xv * wv[3];
  }

  #pragma unroll
  for (int c = 0; c < 4; ++c) tile[cg * 4 + c][r] = f2bf(acc[c]);

  // fused s-vectors
  f32x4 av1 = *(const f32x4*)(a1 + cg * 4);
  f32x4 av2 = *(const f32x4*)(a2 + cg * 4);
  float s1 = acc[0] * av1[0] + acc[1] * av1[1] + acc[2] * av1[2] + acc[3] * av1[3];
  float s2 = acc[0] * av2[0] + acc[1] * av2[1] + acc[2] * av2[2] + acc[3] * av2[3];
  #pragma unroll
  for (int off = 16; off > 0; off >>= 1) {
    s1 += __shfl_xor(s1, off, 64);
    s2 += __shfl_xor(s2, off, 64);
  }
  if (cg == 0) {
    const int row = rowbase + r;
    float c0 = s1 + SHIFT;
    float c = fmaxf(c0, SLOPE * c0);
    f32x4 ev;
    ev[0] = __expf(s1 - c);
    ev[1] = __expf(SLOPE * s1 - c);
    ev[2] = __expf(-s1);
    ev[3] = 0.f;
    *(f32x4*)(Etab + (size_t)row * 4) = ev;
    Ftab[(size_t)row * 2]     = __expf(s2);
    Ftab[(size_t)row * 2 + 1] = __expf(SLOPE * s2);
  }
  __syncthreads();

  // transposed store: thread f<128 stores ht[f][rowbase..rowbase+7] (16 B)
  if (tid < 128) {
    u32x4 v = *(const u32x4*)&tile[tid][0];
    *(u32x4*)(ht + (size_t)tid * NN + rowbase) = v;
  }
}

// ---------------------------------------------------------------------------
// Kernel C: fused masked-softmax aggregation, v4.
//  * 512 blocks x 4 waves; block owns 16 rows; wave jq owns j-quarter,
//    ALL 128 f (8 tiles) -> waves fully independent, NO barriers in the loop.
//  * all inner-loop sources are cache-resident: mask bits (8 MB, L2/L3),
//    ht (2 MB, L2), Ftab slice (16 KB, L1), zero HBM streaming.
//  * weight = (pos?E:E2)*(pos?F:F2), pos <=> F >= Einv  -- no exp, ~7 VALU.
//  * denominator via ones-MFMA on the same af (layout-proof, as round 2);
//    C/D slot mapping from runtime probe MFMAs (as round 2, which passed).
// ---------------------------------------------------------------------------
__global__ __launch_bounds__(256, 2) void k_gat(const unsigned int* __restrict__ mask,
                                                const unsigned short* __restrict__ ht,
                                                const float* __restrict__ Etab,
                                                const float* __restrict__ Ftab,
                                                const float* __restrict__ bias,
                                                float* __restrict__ out) {
  __shared__ float accs[4][16][128];
  __shared__ float dpart[4][16];

  const int tid = threadIdx.x;
  const int jq = tid >> 6;          // wave = j-quarter
  const int lane = tid & 63;
  const int quad = lane >> 4;
  const int m = lane & 15;
  const int rowbase = blockIdx.x * 16;
  const int row = rowbase + m;

  // ---- runtime layout probes (exact) ----
  bf16x8 pm, pinv, pones;
  #pragma unroll
  for (int jj = 0; jj < 8; ++jj) {
    pm[jj] = (__bf16)(float)m;
    pinv[jj] = (__bf16)0.03125f;
    pones[jj] = (__bf16)1.0f;
  }
  f32x4 z = {0.f, 0.f, 0.f, 0.f};
  f32x4 rp = __builtin_amdgcn_mfma_f32_16x16x32_bf16(pm, pinv, z, 0, 0, 0);
  f32x4 cp = __builtin_amdgcn_mfma_f32_16x16x32_bf16(pinv, pm, z, 0, 0, 0);
  int rowmap[4], colmap[4];
  #pragma unroll
  for (int r = 0; r < 4; ++r) {
    rowmap[r] = ((int)(rp[r] + 0.5f)) & 15;
    colmap[r] = ((int)(cp[r] + 0.5f)) & 15;
  }

  f32x4 ev = *(const f32x4*)(Etab + (size_t)row * 4);
  const float E = ev[0], E2 = ev[1], Einv = ev[2];

  // base pointers for this wave's j-quarter
  const unsigned int* maskp = mask + (size_t)row * 256 + jq * 64;       // dwords
  const float* Fp = Ftab + (size_t)(jq * 2048 + quad * 8) * 2;          // float pairs
  const unsigned short* hb[8];
  #pragma unroll
  for (int t = 0; t < 8; ++t)
    hb[t] = ht + (size_t)(t * 16 + m) * NN + jq * 2048 + quad * 8;

  f32x4 acc[8];
  #pragma unroll
  for (int t = 0; t < 8; ++t) acc[t] = z;
  f32x4 den = z;

  for (int k4 = 0; k4 < 16; ++k4) {
    u32x4 mrow4 = *(const u32x4*)(maskp + k4 * 4);   // 4 dwords = 16 k-steps... (4 k's)
    #pragma unroll
    for (int ku = 0; ku < 4; ++ku) {
      const int k = k4 * 4 + ku;
      const unsigned mbyte = (mrow4[ku] >> (quad * 8)) & 0xffu;

      // F/F2 pairs for j = jq*2048 + k*32 + quad*8 + [0..8)
      const float* fb = Fp + (size_t)k * 64;   // 32 j * 2 floats
      f32x4 fq0 = *(const f32x4*)(fb);
      f32x4 fq1 = *(const f32x4*)(fb + 4);
      f32x4 fq2 = *(const f32x4*)(fb + 8);
      f32x4 fq3 = *(const f32x4*)(fb + 12);

      bf16x8 af;
      #pragma unroll
      for (int jj = 0; jj < 8; ++jj) {
        float F, F2;
        switch (jj >> 1) {
          case 0: F = fq0[(jj & 1) * 2]; F2 = fq0[(jj & 1) * 2 + 1]; break;
          case 1: F = fq1[(jj & 1) * 2]; F2 = fq1[(jj & 1) * 2 + 1]; break;
          case 2: F = fq2[(jj & 1) * 2]; F2 = fq2[(jj & 1) * 2 + 1]; break;
          default: F = fq3[(jj & 1) * 2]; F2 = fq3[(jj & 1) * 2 + 1]; break;
        }
        bool pos = (F >= Einv);                   // <=> s1 + s2 >= 0
        float w = (pos ? E : E2) * (pos ? F : F2);
        af[jj] = ((mbyte >> jj) & 1u) ? (__bf16)w : (__bf16)0.0f;
      }

      #pragma unroll
      for (int t = 0; t < 8; ++t) {
        bf16x8 bfr = __builtin_bit_cast(bf16x8, *(const u32x4*)(hb[t] + k * 32));
        acc[t] = __builtin_amdgcn_mfma_f32_16x16x32_bf16(af, bfr, acc[t], 0, 0, 0);
      }
      den = __builtin_amdgcn_mfma_f32_16x16x32_bf16(af, pones, den, 0, 0, 0);
    }
  }

  // ---- epilogue: cross-wave combine over j-quarters ----
  #pragma unroll
  for (int t = 0; t < 8; ++t)
    #pragma unroll
    for (int r = 0; r < 4; ++r)
      accs[jq][rowmap[r]][t * 16 + colmap[r]] = acc[t][r];
  if (m == 0) {
    #pragma unroll
    for (int r = 0; r < 4; ++r)
      dpart[jq][rowmap[r]] = den[r];
  }
  __syncthreads();

  #pragma unroll
  for (int p = 0; p < 8; ++p) {
    int idx = p * 256 + tid;
    int r2 = idx >> 7, col = idx & 127;
    float v = accs[0][r2][col] + accs[1][r2][col] +
              accs[2][r2][col] + accs[3][r2][col];
    float l = dpart[0][r2] + dpart[1][r2] + dpart[2][r2] + dpart[3][r2];
    out[(size_t)(rowbase + r2) * FOUT + col] = v / l + bias[col];
  }
}

// ---------------------------------------------------------------------------
extern "C" void kernel_launch(void* const* d_in, const int* in_sizes, int n_in,
                              void* d_out, int out_size, void* d_ws, size_t ws_size,
                              hipStream_t stream) {
  const float* x    = (const float*)d_in[0];
  const int*   adj  = (const int*)d_in[1];
  const float* W    = (const float*)d_in[2];
  const float* a1   = (const float*)d_in[3];
  const float* a2   = (const float*)d_in[4];
  const float* bias = (const float*)d_in[5];
  float* out = (float*)d_out;

  char* ws = (char*)d_ws;
  unsigned long long* maskq = (unsigned long long*)ws;           // 8 MB
  unsigned short* ht = (unsigned short*)(ws + (size_t)8 * 1024 * 1024);  // 2 MB
  float* Etab = (float*)(ws + (size_t)10 * 1024 * 1024);         // 128 KB
  float* Ftab = (float*)(ws + (size_t)10 * 1024 * 1024 + 128 * 1024);   // 64 KB

  k_pack<<<2048, 256, 0, stream>>>(adj, maskq);
  k_hw<<<NN / 8, 256, 0, stream>>>(x, W, a1, a2, ht, Etab, Ftab);
  k_gat<<<NN / 16, 256, 0, stream>>>((const unsigned int*)maskq, ht, Etab, Ftab,
                                     bias, out);
}

// Round 5
// 517.617 us; speedup vs baseline: 1.0949x; 1.0949x over previous
//
#include <hip/hip_runtime.h>
#include <cstdint>
#include <cstddef>

#define NN 8192
#define FIN 256
#define FOUT 128
#define SLOPE 0.2f
#define SHIFT 8.0f

typedef float f32x4 __attribute__((ext_vector_type(4)));
typedef __bf16 bf16x8 __attribute__((ext_vector_type(8)));
typedef int i32x4 __attribute__((ext_vector_type(4)));
typedef unsigned int u32x4 __attribute__((ext_vector_type(4)));

__device__ __forceinline__ unsigned short f2bf(float f) {
  return __builtin_bit_cast(unsigned short, (__bf16)f);
}

// ---------------------------------------------------------------------------
// Kernel A: h = x @ W (fp32 acc) -> ht[FOUT][NN] bf16 (transposed), plus fused
// s-reductions and the E/F exp-factor tables:
//   Etab[row] = (E, E2, Einv, 0) = (e^{s1-c}, e^{0.2 s1 - c}, e^{-s1}, 0),
//     c = leakyrelu(s1 + SHIFT)  (>= row max of leakyrelu(s1+s2))
//   Ftab[2j,2j+1] = (e^{s2}, e^{0.2 s2})
// so exp(leakyrelu(s1+s2) - c) = (pos?E:E2)*(pos?F:F2), pos <=> F >= Einv.
// ---------------------------------------------------------------------------
__global__ __launch_bounds__(256, 4) void k_hw(const float* __restrict__ x,
                                               const float* __restrict__ W,
                                               const float* __restrict__ a1,
                                               const float* __restrict__ a2,
                                               unsigned short* __restrict__ ht,
                                               float* __restrict__ Etab,
                                               float* __restrict__ Ftab) {
  __shared__ float xs[8][256];
  __shared__ unsigned short tile[128][8];   // [f][row]
  const int tid = threadIdx.x;
  const int rowbase = blockIdx.x * 8;

  #pragma unroll
  for (int it = 0; it < 2; ++it) {
    int fi = it * 1024 + tid * 4;
    int r = fi >> 8, k = fi & 255;
    *(f32x4*)&xs[r][k] = *(const f32x4*)(x + (size_t)(rowbase + r) * FIN + k);
  }
  __syncthreads();

  const int r = tid >> 5;    // 0..7
  const int cg = tid & 31;   // cols cg*4..cg*4+3
  f32x4 acc = {0.f, 0.f, 0.f, 0.f};

  #pragma unroll 8
  for (int k = 0; k < FIN; ++k) {
    f32x4 wv = *(const f32x4*)(W + k * FOUT + cg * 4);
    float xv = xs[r][k];
    acc[0] += xv * wv[0];
    acc[1] += xv * wv[1];
    acc[2] += xv * wv[2];
    acc[3] += xv * wv[3];
  }

  #pragma unroll
  for (int c = 0; c < 4; ++c) tile[cg * 4 + c][r] = f2bf(acc[c]);

  // fused s-vectors
  f32x4 av1 = *(const f32x4*)(a1 + cg * 4);
  f32x4 av2 = *(const f32x4*)(a2 + cg * 4);
  float s1 = acc[0] * av1[0] + acc[1] * av1[1] + acc[2] * av1[2] + acc[3] * av1[3];
  float s2 = acc[0] * av2[0] + acc[1] * av2[1] + acc[2] * av2[2] + acc[3] * av2[3];
  #pragma unroll
  for (int off = 16; off > 0; off >>= 1) {
    s1 += __shfl_xor(s1, off, 64);
    s2 += __shfl_xor(s2, off, 64);
  }
  if (cg == 0) {
    const int row = rowbase + r;
    float c0 = s1 + SHIFT;
    float c = fmaxf(c0, SLOPE * c0);
    f32x4 ev;
    ev[0] = __expf(s1 - c);
    ev[1] = __expf(SLOPE * s1 - c);
    ev[2] = __expf(-s1);
    ev[3] = 0.f;
    *(f32x4*)(Etab + (size_t)row * 4) = ev;
    Ftab[(size_t)row * 2]     = __expf(s2);
    Ftab[(size_t)row * 2 + 1] = __expf(SLOPE * s2);
  }
  __syncthreads();

  // transposed store: thread f<128 stores ht[f][rowbase..rowbase+7] (16 B)
  if (tid < 128) {
    u32x4 v = *(const u32x4*)&tile[tid][0];
    *(u32x4*)(ht + (size_t)tid * NN + rowbase) = v;
  }
}

// ---------------------------------------------------------------------------
// Kernel B: fused masked-softmax aggregation, v5.
//  * 512 blocks x 4 waves; block = 16 rows; wave jq = j-quarter (2048 j =
//    64 k-steps of 32 j). No barriers in the loop; epilogue LDS combine.
//  * EXPLICIT 1-deep register software pipeline: all loads for k-step k+1
//    (2 adj nontemporal + 4 Ftab + 8 ht) are issued before the compute of
//    k-step k, so the waitcnt before compute leaves the next step's loads
//    in flight (never drains the pipe). adj is read directly (no pack pass).
//  * weight = (pos?E:E2)*(pos?F:F2), pos <=> F >= Einv  -- no exp in loop.
//  * denominator via ones-MFMA on the same af (layout-proof, round-2 proven);
//    C/D slot mapping from runtime probe MFMAs.
// ---------------------------------------------------------------------------
__global__ __launch_bounds__(256, 2) void k_gat(const int* __restrict__ adj,
                                                const unsigned short* __restrict__ ht,
                                                const float* __restrict__ Etab,
                                                const float* __restrict__ Ftab,
                                                const float* __restrict__ bias,
                                                float* __restrict__ out) {
  __shared__ float accs[4][16][128];
  __shared__ float dpart[4][16];

  const int tid = threadIdx.x;
  const int jq = tid >> 6;          // wave = j-quarter
  const int lane = tid & 63;
  const int quad = lane >> 4;
  const int m = lane & 15;
  const int rowbase = blockIdx.x * 16;
  const int row = rowbase + m;

  // ---- runtime layout probes (exact in bf16/fp32) ----
  bf16x8 pm, pinv, pones;
  #pragma unroll
  for (int jj = 0; jj < 8; ++jj) {
    pm[jj] = (__bf16)(float)m;
    pinv[jj] = (__bf16)0.03125f;
    pones[jj] = (__bf16)1.0f;
  }
  f32x4 z = {0.f, 0.f, 0.f, 0.f};
  f32x4 rp = __builtin_amdgcn_mfma_f32_16x16x32_bf16(pm, pinv, z, 0, 0, 0);
  f32x4 cp = __builtin_amdgcn_mfma_f32_16x16x32_bf16(pinv, pm, z, 0, 0, 0);
  int rowmap[4], colmap[4];
  #pragma unroll
  for (int r = 0; r < 4; ++r) {
    rowmap[r] = ((int)(rp[r] + 0.5f)) & 15;
    colmap[r] = ((int)(cp[r] + 0.5f)) & 15;
  }

  f32x4 ev = *(const f32x4*)(Etab + (size_t)row * 4);
  const float E = ev[0], E2 = ev[1], Einv = ev[2];

  const int jbase = jq * 2048 + quad * 8;
  const int* ap = adj + (size_t)row * NN + jbase;
  const float* Fp = Ftab + (size_t)jbase * 2;
  const unsigned short* hb[8];
  #pragma unroll
  for (int t = 0; t < 8; ++t)
    hb[t] = ht + (size_t)(t * 16 + m) * NN + jbase;

  f32x4 acc[8];
  #pragma unroll
  for (int t = 0; t < 8; ++t) acc[t] = z;
  f32x4 den = z;

  // ---- software-pipeline registers (double buffer) ----
  i32x4 pa0[2], pa1[2];
  f32x4 pf0[2], pf1[2], pf2[2], pf3[2];
  u32x4 phv[2][8];

  // prologue: k-step 0 -> slot 0
  pa0[0] = __builtin_nontemporal_load((const i32x4*)ap);
  pa1[0] = __builtin_nontemporal_load((const i32x4*)(ap + 4));
  pf0[0] = *(const f32x4*)(Fp);
  pf1[0] = *(const f32x4*)(Fp + 4);
  pf2[0] = *(const f32x4*)(Fp + 8);
  pf3[0] = *(const f32x4*)(Fp + 12);
  #pragma unroll
  for (int t = 0; t < 8; ++t) phv[0][t] = *(const u32x4*)(hb[t]);

  #pragma unroll 2
  for (int k = 0; k < 64; ++k) {
    const int cs = k & 1, ns = cs ^ 1;
    if (k + 1 < 64) {
      const int o = (k + 1) * 32;
      pa0[ns] = __builtin_nontemporal_load((const i32x4*)(ap + o));
      pa1[ns] = __builtin_nontemporal_load((const i32x4*)(ap + o + 4));
      const float* fb = Fp + (size_t)(k + 1) * 64;
      pf0[ns] = *(const f32x4*)(fb);
      pf1[ns] = *(const f32x4*)(fb + 4);
      pf2[ns] = *(const f32x4*)(fb + 8);
      pf3[ns] = *(const f32x4*)(fb + 12);
      #pragma unroll
      for (int t = 0; t < 8; ++t) phv[ns][t] = *(const u32x4*)(hb[t] + o);
    }

    bf16x8 af;
    #pragma unroll
    for (int jj = 0; jj < 8; ++jj) {
      float F, F2;
      switch (jj >> 1) {
        case 0:  F = pf0[cs][(jj & 1) * 2]; F2 = pf0[cs][(jj & 1) * 2 + 1]; break;
        case 1:  F = pf1[cs][(jj & 1) * 2]; F2 = pf1[cs][(jj & 1) * 2 + 1]; break;
        case 2:  F = pf2[cs][(jj & 1) * 2]; F2 = pf2[cs][(jj & 1) * 2 + 1]; break;
        default: F = pf3[cs][(jj & 1) * 2]; F2 = pf3[cs][(jj & 1) * 2 + 1]; break;
      }
      int av = (jj < 4) ? pa0[cs][jj] : pa1[cs][jj - 4];
      bool pos = (F >= Einv);                   // <=> s1 + s2 >= 0
      float w = (pos ? E : E2) * (pos ? F : F2);
      af[jj] = (av != 0) ? (__bf16)w : (__bf16)0.0f;
    }

    #pragma unroll
    for (int t = 0; t < 8; ++t) {
      bf16x8 bfr = __builtin_bit_cast(bf16x8, phv[cs][t]);
      acc[t] = __builtin_amdgcn_mfma_f32_16x16x32_bf16(af, bfr, acc[t], 0, 0, 0);
    }
    den = __builtin_amdgcn_mfma_f32_16x16x32_bf16(af, pones, den, 0, 0, 0);
  }

  // ---- epilogue: cross-wave combine over j-quarters ----
  #pragma unroll
  for (int t = 0; t < 8; ++t)
    #pragma unroll
    for (int r = 0; r < 4; ++r)
      accs[jq][rowmap[r]][t * 16 + colmap[r]] = acc[t][r];
  if (m == 0) {
    #pragma unroll
    for (int r = 0; r < 4; ++r)
      dpart[jq][rowmap[r]] = den[r];
  }
  __syncthreads();

  #pragma unroll
  for (int p = 0; p < 8; ++p) {
    int idx = p * 256 + tid;
    int r2 = idx >> 7, col = idx & 127;
    float v = accs[0][r2][col] + accs[1][r2][col] +
              accs[2][r2][col] + accs[3][r2][col];
    float l = dpart[0][r2] + dpart[1][r2] + dpart[2][r2] + dpart[3][r2];
    out[(size_t)(rowbase + r2) * FOUT + col] = v / l + bias[col];
  }
}

// ---------------------------------------------------------------------------
extern "C" void kernel_launch(void* const* d_in, const int* in_sizes, int n_in,
                              void* d_out, int out_size, void* d_ws, size_t ws_size,
                              hipStream_t stream) {
  const float* x    = (const float*)d_in[0];
  const int*   adj  = (const int*)d_in[1];
  const float* W    = (const float*)d_in[2];
  const float* a1   = (const float*)d_in[3];
  const float* a2   = (const float*)d_in[4];
  const float* bias = (const float*)d_in[5];
  float* out = (float*)d_out;

  char* ws = (char*)d_ws;
  unsigned short* ht = (unsigned short*)ws;                        // 2 MB
  float* Etab = (float*)(ws + (size_t)2 * 1024 * 1024);            // 128 KB
  float* Ftab = (float*)(ws + (size_t)2 * 1024 * 1024 + 128 * 1024); // 64 KB

  k_hw<<<NN / 8, 256, 0, stream>>>(x, W, a1, a2, ht, Etab, Ftab);
  k_gat<<<NN / 16, 256, 0, stream>>>(adj, ht, Etab, Ftab, bias, out);
}

// Round 7
// 484.567 us; speedup vs baseline: 1.1696x; 1.0682x over previous
//
#include <hip/hip_runtime.h>
#include <cstdint>
#include <cstddef>

#define NN 8192
#define FIN 256
#define FOUT 128
#define SLOPE 0.2f
#define SHIFT 8.0f

typedef float f32x4 __attribute__((ext_vector_type(4)));
typedef __bf16 bf16x8 __attribute__((ext_vector_type(8)));
typedef int i32x4 __attribute__((ext_vector_type(4)));
typedef unsigned int u32x4 __attribute__((ext_vector_type(4)));

__device__ __forceinline__ unsigned short f2bf(float f) {
  return __builtin_bit_cast(unsigned short, (__bf16)f);
}
__device__ __forceinline__ float bf2f(unsigned short u) {
  return (float)__builtin_bit_cast(__bf16, u);
}

// async global->LDS DMA, 16 B/lane; LDS dest = wave-uniform base + lane*16
__device__ __forceinline__ void async_cp16(void* lds, const void* g) {
  __builtin_amdgcn_global_load_lds(
      (const __attribute__((address_space(1))) void*)g,
      (__attribute__((address_space(3))) void*)lds, 16, 0, 0);
}

// ---------------------------------------------------------------------------
// Kernel A: h = x @ W (fp32 acc) -> ht[FOUT][NN] bf16 (transposed), plus fused
// s-reductions and the exp-factor tables:
//   Etab[row] = (E, E2, Einv, 0) = (e^{s1-c}, e^{0.2 s1 - c}, e^{-s1}, 0),
//     c = leakyrelu(s1 + SHIFT)  (>= row max of leakyrelu(s1+s2))
//   Fbf[2j, 2j+1] = bf16(e^{s2_j}), bf16(e^{0.2 s2_j})
// so exp(leakyrelu(s1+s2) - c) = (pos?E:E2)*(pos?F:F2), pos <=> F >= Einv.
// ---------------------------------------------------------------------------
__global__ __launch_bounds__(256, 4) void k_hw(const float* __restrict__ x,
                                               const float* __restrict__ W,
                                               const float* __restrict__ a1,
                                               const float* __restrict__ a2,
                                               unsigned short* __restrict__ ht,
                                               float* __restrict__ Etab,
                                               unsigned short* __restrict__ Fbf) {
  __shared__ float xs[8][256];
  __shared__ unsigned short tile[128][8];   // [f][row]
  const int tid = threadIdx.x;
  const int rowbase = blockIdx.x * 8;

  #pragma unroll
  for (int it = 0; it < 2; ++it) {
    int fi = it * 1024 + tid * 4;
    int r = fi >> 8, k = fi & 255;
    *(f32x4*)&xs[r][k] = *(const f32x4*)(x + (size_t)(rowbase + r) * FIN + k);
  }
  __syncthreads();

  const int r = tid >> 5;    // 0..7
  const int cg = tid & 31;   // cols cg*4..cg*4+3
  f32x4 acc = {0.f, 0.f, 0.f, 0.f};

  #pragma unroll 8
  for (int k = 0; k < FIN; ++k) {
    f32x4 wv = *(const f32x4*)(W + k * FOUT + cg * 4);
    float xv = xs[r][k];
    acc[0] += xv * wv[0];
    acc[1] += xv * wv[1];
    acc[2] += xv * wv[2];
    acc[3] += xv * wv[3];
  }

  #pragma unroll
  for (int c = 0; c < 4; ++c) tile[cg * 4 + c][r] = f2bf(acc[c]);

  // fused s-vectors
  f32x4 av1 = *(const f32x4*)(a1 + cg * 4);
  f32x4 av2 = *(const f32x4*)(a2 + cg * 4);
  float s1 = acc[0] * av1[0] + acc[1] * av1[1] + acc[2] * av1[2] + acc[3] * av1[3];
  float s2 = acc[0] * av2[0] + acc[1] * av2[1] + acc[2] * av2[2] + acc[3] * av2[3];
  #pragma unroll
  for (int off = 16; off > 0; off >>= 1) {
    s1 += __shfl_xor(s1, off, 64);
    s2 += __shfl_xor(s2, off, 64);
  }
  if (cg == 0) {
    const int row = rowbase + r;
    float c0 = s1 + SHIFT;
    float c = fmaxf(c0, SLOPE * c0);
    f32x4 ev;
    ev[0] = __expf(s1 - c);
    ev[1] = __expf(SLOPE * s1 - c);
    ev[2] = __expf(-s1);
    ev[3] = 0.f;
    *(f32x4*)(Etab + (size_t)row * 4) = ev;
    Fbf[(size_t)row * 2]     = f2bf(__expf(s2));
    Fbf[(size_t)row * 2 + 1] = f2bf(__expf(SLOPE * s2));
  }
  __syncthreads();

  if (tid < 128) {
    u32x4 v = *(const u32x4*)&tile[tid][0];
    *(u32x4*)(ht + (size_t)tid * NN + rowbase) = v;
  }
}

// ---------------------------------------------------------------------------
// Kernel B: fused masked-softmax aggregation, v7 (= v6 with the F-pair unpack
// fixed: one (F,F2) pair per u32, so the u32 index is jj&3, NOT (jj&3)>>1).
//  * ALL inner-loop operands go global->LDS via global_load_lds (vmcnt FIFO,
//    zero VGPR cost); inner loop reads LDS only (lgkmcnt) -> load latency is
//    hidden by the DMA queue, not by registers.
//  * 512 blocks x 4 waves; block = 16 rows; waves split f-tiles (wave w owns
//    tiles 2w,2w+1) -> adj/ht/F chunk tiles are SHARED, staged once; each
//    wave covers the FULL j range for its tiles -> no cross-wave combine.
//  * chunk = 64 j; double-buffered LDS (40.5 KB -> 2 blocks/CU); one
//    __syncthreads per chunk (m97 pattern).
//  * adj read directly from HBM exactly once.
//  * XOR-swizzled LDS layouts: swizzle folded into the per-lane GLOBAL source
//    address (unconstrained), LDS dest stays contiguous lane*16.
//  * weight = (pos?E:E2)*(pos?F:F2), pos <=> F >= Einv -- no exp in loop.
//  * denominator via ones-MFMA on the same af; C/D slot maps from runtime
//    probe MFMAs (R2-proven).
// ---------------------------------------------------------------------------
__global__ __launch_bounds__(256, 2) void k_gat(const int* __restrict__ adj,
                                                const unsigned short* __restrict__ ht,
                                                const float* __restrict__ Etab,
                                                const unsigned short* __restrict__ Fbf,
                                                const float* __restrict__ bias,
                                                float* __restrict__ out) {
  __shared__ int sA[2][16 * 64];            // 8 KB  : adj, slot s holds group s^row
  __shared__ unsigned short sH[2][128 * 64];// 32 KB : ht,  slot s holds group s^(f&7)
  __shared__ unsigned short sF[2][128];     // 0.5 KB: F-pairs, linear

  const int tid = threadIdx.x;
  const int wave = tid >> 6;
  const int lane = tid & 63;
  const int quad = lane >> 4;
  const int m = lane & 15;                  // A-row / B-col label
  const int rowbase = blockIdx.x * 16;
  const int row = rowbase + m;

  // ---- runtime layout probes (exact in bf16/fp32) ----
  bf16x8 pm, pinv, pones;
  #pragma unroll
  for (int jj = 0; jj < 8; ++jj) {
    pm[jj] = (__bf16)(float)m;
    pinv[jj] = (__bf16)0.03125f;
    pones[jj] = (__bf16)1.0f;
  }
  f32x4 z = {0.f, 0.f, 0.f, 0.f};
  f32x4 rp = __builtin_amdgcn_mfma_f32_16x16x32_bf16(pm, pinv, z, 0, 0, 0);
  f32x4 cp = __builtin_amdgcn_mfma_f32_16x16x32_bf16(pinv, pm, z, 0, 0, 0);
  int rowmap[4], colmap[4];
  #pragma unroll
  for (int r = 0; r < 4; ++r) {
    rowmap[r] = ((int)(rp[r] + 0.5f)) & 15;
    colmap[r] = ((int)(cp[r] + 0.5f)) & 15;
  }

  f32x4 ev = *(const f32x4*)(Etab + (size_t)row * 4);
  const float E = ev[0], E2 = ev[1], Einv = ev[2];

  const int t0 = wave * 2, t1 = wave * 2 + 1;

  f32x4 acc0 = z, acc1 = z, den = z;

  // ---- staging: chunk c -> buffer b ----
  auto stage = [&](int c, int b) {
    // ht tile: wave w stages f-rows 32w..32w+31 (4 instrs, 1 KB each).
    // lane L of instr i (global i = 4w+il): f = 8i + L/8, group g = (L%8)^(L/8)
    #pragma unroll
    for (int il = 0; il < 4; ++il) {
      const int i = wave * 4 + il;
      const int f = i * 8 + (lane >> 3);
      const int g = (lane & 7) ^ (lane >> 3);
      async_cp16(&sH[b][i * 512],  // i*1024 B
                 ht + (size_t)f * NN + c * 64 + g * 8);
    }
    if (wave == 0) {
      // adj tile: lane of instr il: r = 4il + L/16, slot s = L%16,
      // group g = s ^ r  (slot s of row r holds global group s^r)
      #pragma unroll
      for (int il = 0; il < 4; ++il) {
        const int r = il * 4 + (lane >> 4);
        const int g = (lane & 15) ^ r;
        async_cp16(&sA[b][il * 256],  // il*1024 B
                   adj + (size_t)(rowbase + r) * NN + c * 64 + g * 4);
      }
    } else if (wave == 1 && lane < 16) {
      // F pairs: 256 B, linear (reads are broadcast -> no swizzle needed)
      async_cp16(&sF[b][0], Fbf + (size_t)c * 128 + lane * 8);
    }
  };

  stage(0, 0);
  __syncthreads();   // chunk 0 DMA drained

  for (int c = 0; c < 128; ++c) {
    const int cs = c & 1, ns = cs ^ 1;
    if (c + 1 < 128) stage(c + 1, ns);

    #pragma unroll
    for (int k32 = 0; k32 < 2; ++k32) {
      // adj: row m, j-local k32*32+quad*8 .. +8 -> groups g0,g0+1, slots g^m
      const int g0 = k32 * 8 + quad * 2;
      i32x4 A0 = *(const i32x4*)&sA[cs][m * 64 + ((g0) ^ m) * 4];
      i32x4 A1 = *(const i32x4*)&sA[cs][m * 64 + ((g0 + 1) ^ m) * 4];
      // F pairs: shorts [g0*8, g0*8+8) = pairs for jj=0..3; next 8 = jj=4..7
      u32x4 Fq0 = *(const u32x4*)&sF[cs][g0 * 8];
      u32x4 Fq1 = *(const u32x4*)&sF[cs][(g0 + 1) * 8];

      bf16x8 af;
      #pragma unroll
      for (int jj = 0; jj < 8; ++jj) {
        const u32x4& Fq = (jj < 4) ? Fq0 : Fq1;
        const unsigned pk = Fq[jj & 3];         // one (F,F2) pair per u32
        float F  = bf2f((unsigned short)(pk & 0xffffu));
        float F2 = bf2f((unsigned short)(pk >> 16));
        int av = (jj < 4) ? A0[jj] : A1[jj - 4];
        bool pos = (F >= Einv);                 // <=> s1 + s2 >= 0
        float w = (pos ? E : E2) * (pos ? F : F2);
        af[jj] = (av != 0) ? (__bf16)w : (__bf16)0.0f;
      }

      // ht frags: tile t, slot s = (4k32+quad) ^ (m&7)
      const int gp = k32 * 4 + quad;
      const int s0 = gp ^ (m & 7);
      bf16x8 b0 = __builtin_bit_cast(bf16x8,
          *(const u32x4*)&sH[cs][(t0 * 16 + m) * 64 + s0 * 8]);
      bf16x8 b1 = __builtin_bit_cast(bf16x8,
          *(const u32x4*)&sH[cs][(t1 * 16 + m) * 64 + s0 * 8]);

      acc0 = __builtin_amdgcn_mfma_f32_16x16x32_bf16(af, b0, acc0, 0, 0, 0);
      acc1 = __builtin_amdgcn_mfma_f32_16x16x32_bf16(af, b1, acc1, 0, 0, 0);
      den  = __builtin_amdgcn_mfma_f32_16x16x32_bf16(af, pones, den, 0, 0, 0);
    }
    __syncthreads();   // drains chunk c+1 DMA; fences buffer cs reuse
  }

  // ---- epilogue: wave-private rows x cols, direct store ----
  #pragma unroll
  for (int r = 0; r < 4; ++r) {
    const float inv = 1.0f / den[r];
    const int orow = rowbase + rowmap[r];
    const int c0 = t0 * 16 + colmap[r];
    const int c1 = t1 * 16 + colmap[r];
    out[(size_t)orow * FOUT + c0] = acc0[r] * inv + bias[c0];
    out[(size_t)orow * FOUT + c1] = acc1[r] * inv + bias[c1];
  }
}

// ---------------------------------------------------------------------------
extern "C" void kernel_launch(void* const* d_in, const int* in_sizes, int n_in,
                              void* d_out, int out_size, void* d_ws, size_t ws_size,
                              hipStream_t stream) {
  const float* x    = (const float*)d_in[0];
  const int*   adj  = (const int*)d_in[1];
  const float* W    = (const float*)d_in[2];
  const float* a1   = (const float*)d_in[3];
  const float* a2   = (const float*)d_in[4];
  const float* bias = (const float*)d_in[5];
  float* out = (float*)d_out;

  char* ws = (char*)d_ws;
  unsigned short* ht = (unsigned short*)ws;                          // 2 MB
  float* Etab = (float*)(ws + (size_t)2 * 1024 * 1024);              // 128 KB
  unsigned short* Fbf =
      (unsigned short*)(ws + (size_t)2 * 1024 * 1024 + 128 * 1024);  // 32 KB

  k_hw<<<NN / 8, 256, 0, stream>>>(x, W, a1, a2, ht, Etab, Fbf);
  k_gat<<<NN / 16, 256, 0, stream>>>(adj, ht, Etab, Fbf, bias, out);
}

// Round 8
// 478.108 us; speedup vs baseline: 1.1854x; 1.0135x over previous
//
#include <hip/hip_runtime.h>
#include <cstdint>
#include <cstddef>

#define NN 8192
#define FIN 256
#define FOUT 128
#define SLOPE 0.2f
#define SHIFT 8.0f

typedef float f32x4 __attribute__((ext_vector_type(4)));
typedef __bf16 bf16x8 __attribute__((ext_vector_type(8)));
typedef int i32x4 __attribute__((ext_vector_type(4)));
typedef unsigned int u32x4 __attribute__((ext_vector_type(4)));

__device__ __forceinline__ unsigned short f2bf(float f) {
  return __builtin_bit_cast(unsigned short, (__bf16)f);
}

// async global->LDS DMA, 16 B/lane; LDS dest = wave-uniform base + lane*16
__device__ __forceinline__ void async_cp16(void* lds, const void* g) {
  __builtin_amdgcn_global_load_lds(
      (const __attribute__((address_space(1))) void*)g,
      (__attribute__((address_space(3))) void*)lds, 16, 0, 0);
}

// ---------------------------------------------------------------------------
// Kernel A: h = x @ W (fp32 acc) -> ht[FOUT][NN] bf16 (transposed), plus fused
// s-reductions and the exp-factor tables:
//   Etab[2row,2row+1] = (E, E2) = (e^{s1-c}, e^{0.2 s1 - c}),
//     c = leakyrelu(s1 + SHIFT)  (>= row max of leakyrelu(s1+s2))
//   FbfF[j] = bf16(e^{s2_j}),  FbfF2[j] = bf16(e^{0.2 s2_j})   (two planes)
// so exp(leakyrelu(s1+s2) - c) = max(E*F, E2*F2)  (exp monotone, exact).
// ---------------------------------------------------------------------------
__global__ __launch_bounds__(256, 4) void k_hw(const float* __restrict__ x,
                                               const float* __restrict__ W,
                                               const float* __restrict__ a1,
                                               const float* __restrict__ a2,
                                               unsigned short* __restrict__ ht,
                                               float* __restrict__ Etab,
                                               unsigned short* __restrict__ FbfF,
                                               unsigned short* __restrict__ FbfF2) {
  __shared__ float xs[8][256];
  __shared__ unsigned short tile[128][8];   // [f][row]
  const int tid = threadIdx.x;
  const int rowbase = blockIdx.x * 8;

  #pragma unroll
  for (int it = 0; it < 2; ++it) {
    int fi = it * 1024 + tid * 4;
    int r = fi >> 8, k = fi & 255;
    *(f32x4*)&xs[r][k] = *(const f32x4*)(x + (size_t)(rowbase + r) * FIN + k);
  }
  __syncthreads();

  const int r = tid >> 5;    // 0..7
  const int cg = tid & 31;   // cols cg*4..cg*4+3
  f32x4 acc = {0.f, 0.f, 0.f, 0.f};

  #pragma unroll 8
  for (int k = 0; k < FIN; ++k) {
    f32x4 wv = *(const f32x4*)(W + k * FOUT + cg * 4);
    float xv = xs[r][k];
    acc[0] += xv * wv[0];
    acc[1] += xv * wv[1];
    acc[2] += xv * wv[2];
    acc[3] += xv * wv[3];
  }

  #pragma unroll
  for (int c = 0; c < 4; ++c) tile[cg * 4 + c][r] = f2bf(acc[c]);

  // fused s-vectors
  f32x4 av1 = *(const f32x4*)(a1 + cg * 4);
  f32x4 av2 = *(const f32x4*)(a2 + cg * 4);
  float s1 = acc[0] * av1[0] + acc[1] * av1[1] + acc[2] * av1[2] + acc[3] * av1[3];
  float s2 = acc[0] * av2[0] + acc[1] * av2[1] + acc[2] * av2[2] + acc[3] * av2[3];
  #pragma unroll
  for (int off = 16; off > 0; off >>= 1) {
    s1 += __shfl_xor(s1, off, 64);
    s2 += __shfl_xor(s2, off, 64);
  }
  if (cg == 0) {
    const int row = rowbase + r;
    float c0 = s1 + SHIFT;
    float c = fmaxf(c0, SLOPE * c0);
    Etab[(size_t)row * 2]     = __expf(s1 - c);
    Etab[(size_t)row * 2 + 1] = __expf(SLOPE * s1 - c);
    FbfF[row]  = f2bf(__expf(s2));
    FbfF2[row] = f2bf(__expf(SLOPE * s2));
  }
  __syncthreads();

  if (tid < 128) {
    u32x4 v = *(const u32x4*)&tile[tid][0];
    *(u32x4*)(ht + (size_t)tid * NN + rowbase) = v;
  }
}

// ---------------------------------------------------------------------------
// Kernel B: fused masked-softmax aggregation, v8.
// Delta vs v7 (which passed, bank conflicts 0):
//  * PIPELINE ORDER FIX: per chunk, barrier FIRST (drains only chunk c's DMA,
//    issued a full compute-phase ago), THEN issue stage(c+1), THEN compute(c).
//    The prefetch now flies ACROSS the barrier instead of being drained by it.
//  * weight = max(E*F, E2*F2)  -- exp(lrelu)-identity, removes Einv compare
//    chain (fewer VALU, exactly equivalent math).
//  * F/F2 stored as separate bf16 planes -> 1-shift unpack per element.
//  * staging DMA rebalanced: ht 4/wave; adj on waves 2,3; F on wave 1.
//  * denominator via ones-MFMA on the same af (slot-consistent); C/D slot
//    maps from runtime probe MFMAs (R2-proven machinery, unchanged).
// ---------------------------------------------------------------------------
__global__ __launch_bounds__(256, 2) void k_gat(const int* __restrict__ adj,
                                                const unsigned short* __restrict__ ht,
                                                const float* __restrict__ Etab,
                                                const unsigned short* __restrict__ FbfF,
                                                const unsigned short* __restrict__ FbfF2,
                                                const float* __restrict__ bias,
                                                float* __restrict__ out) {
  __shared__ int sA[2][16 * 64];             // 8 KB  : adj, slot s holds group s^row
  __shared__ unsigned short sH[2][128 * 64]; // 32 KB : ht,  slot s holds group s^(f&7)
  __shared__ unsigned short sF[2][128];      // 0.5 KB: [0,64)=F plane, [64,128)=F2 plane

  const int tid = threadIdx.x;
  const int wave = tid >> 6;
  const int lane = tid & 63;
  const int quad = lane >> 4;
  const int m = lane & 15;                   // A-row / B-col label
  const int rowbase = blockIdx.x * 16;
  const int row = rowbase + m;

  // ---- runtime layout probes (exact in bf16/fp32) ----
  bf16x8 pm, pinv, pones;
  #pragma unroll
  for (int jj = 0; jj < 8; ++jj) {
    pm[jj] = (__bf16)(float)m;
    pinv[jj] = (__bf16)0.03125f;
    pones[jj] = (__bf16)1.0f;
  }
  f32x4 z = {0.f, 0.f, 0.f, 0.f};
  f32x4 rp = __builtin_amdgcn_mfma_f32_16x16x32_bf16(pm, pinv, z, 0, 0, 0);
  f32x4 cp = __builtin_amdgcn_mfma_f32_16x16x32_bf16(pinv, pm, z, 0, 0, 0);
  int rowmap[4], colmap[4];
  #pragma unroll
  for (int r = 0; r < 4; ++r) {
    rowmap[r] = ((int)(rp[r] + 0.5f)) & 15;
    colmap[r] = ((int)(cp[r] + 0.5f)) & 15;
  }

  const float E  = Etab[(size_t)row * 2];
  const float E2 = Etab[(size_t)row * 2 + 1];

  const int t0 = wave * 2, t1 = wave * 2 + 1;

  f32x4 acc0 = z, acc1 = z, den = z;

  // ---- loop-carried per-lane DMA source pointers ----
  // ht: wave w stages f-rows 32w..32w+31; lane L of instr il:
  //   f = (4w+il)*8 + L/8, group g = (L%8)^(L/8)  (XOR swizzle in source addr)
  const unsigned short* srcH[4];
  #pragma unroll
  for (int il = 0; il < 4; ++il) {
    const int i = wave * 4 + il;
    const int f = i * 8 + (lane >> 3);
    const int g = (lane & 7) ^ (lane >> 3);
    srcH[il] = ht + (size_t)f * NN + g * 8;
  }
  // adj: waves 2,3, two instrs each; instr slot il: r = 4il + L/16,
  //   slot s = L%16 holds group g = s^r
  const int* srcA[2] = {nullptr, nullptr};
  int slotA[2] = {0, 0};
  if (wave >= 2) {
    #pragma unroll
    for (int q = 0; q < 2; ++q) {
      const int il = (wave - 2) * 2 + q;
      const int r = il * 4 + (lane >> 4);
      const int g = (lane & 15) ^ r;
      slotA[q] = il;
      srcA[q] = adj + (size_t)(rowbase + r) * NN + g * 4;
    }
  }
  // F planes: wave 1, lanes 0..15 -> sF[0..255 B]; lanes 0..7 F, 8..15 F2
  const unsigned short* srcF = nullptr;
  if (wave == 1) {
    srcF = (lane < 8) ? (FbfF + lane * 8) : (FbfF2 + (lane - 8) * 8);
  }

  auto stage = [&](int b) {
    #pragma unroll
    for (int il = 0; il < 4; ++il) {
      async_cp16(&sH[b][(wave * 4 + il) * 512], srcH[il]);
      srcH[il] += 64;
    }
    if (wave >= 2) {
      #pragma unroll
      for (int q = 0; q < 2; ++q) {
        async_cp16(&sA[b][slotA[q] * 256], srcA[q]);
        srcA[q] += 64;
      }
    } else if (wave == 1 && lane < 16) {
      async_cp16(&sF[b][0], srcF);
      srcF += 64;
    }
  };

  stage(0);   // chunk 0 -> buffer 0

  for (int c = 0; c < 128; ++c) {
    const int cs = c & 1, ns = cs ^ 1;

    // Barrier FIRST: drains chunk c's DMA (the only outstanding group) and
    // fences all waves' reads of buffer ns (chunk c-1) before its overwrite.
    __syncthreads();
    if (c + 1 < 128) stage(ns);   // prefetch c+1: stays in flight across compute

    #pragma unroll
    for (int k32 = 0; k32 < 2; ++k32) {
      // adj: row m, slots (g)^m for groups g0,g0+1
      const int g0 = k32 * 8 + quad * 2;
      i32x4 A0 = *(const i32x4*)&sA[cs][m * 64 + ((g0) ^ m) * 4];
      i32x4 A1 = *(const i32x4*)&sA[cs][m * 64 + ((g0 + 1) ^ m) * 4];
      // F/F2 planes: j-local jl..jl+7 (broadcast across m)
      const int jl = k32 * 32 + quad * 8;
      u32x4 Fq = *(const u32x4*)&sF[cs][jl];        // 8 bf16 F
      u32x4 Gq = *(const u32x4*)&sF[cs][64 + jl];   // 8 bf16 F2

      bf16x8 af;
      #pragma unroll
      for (int p = 0; p < 4; ++p) {
        const unsigned fp = Fq[p], gp = Gq[p];
        const float Flo = __builtin_bit_cast(float, fp << 16);
        const float Fhi = __builtin_bit_cast(float, fp & 0xffff0000u);
        const float Glo = __builtin_bit_cast(float, gp << 16);
        const float Ghi = __builtin_bit_cast(float, gp & 0xffff0000u);
        const float wlo = fmaxf(E * Flo, E2 * Glo);
        const float whi = fmaxf(E * Fhi, E2 * Ghi);
        const int avlo = (p < 2) ? A0[p * 2] : A1[p * 2 - 4];
        const int avhi = (p < 2) ? A0[p * 2 + 1] : A1[p * 2 - 3];
        af[p * 2]     = avlo ? (__bf16)wlo : (__bf16)0.0f;
        af[p * 2 + 1] = avhi ? (__bf16)whi : (__bf16)0.0f;
      }

      // ht frags: tile t, slot s = (4k32+quad) ^ (m&7)
      const int s0 = (k32 * 4 + quad) ^ (m & 7);
      bf16x8 b0 = __builtin_bit_cast(bf16x8,
          *(const u32x4*)&sH[cs][(t0 * 16 + m) * 64 + s0 * 8]);
      bf16x8 b1 = __builtin_bit_cast(bf16x8,
          *(const u32x4*)&sH[cs][(t1 * 16 + m) * 64 + s0 * 8]);

      acc0 = __builtin_amdgcn_mfma_f32_16x16x32_bf16(af, b0, acc0, 0, 0, 0);
      acc1 = __builtin_amdgcn_mfma_f32_16x16x32_bf16(af, b1, acc1, 0, 0, 0);
      den  = __builtin_amdgcn_mfma_f32_16x16x32_bf16(af, pones, den, 0, 0, 0);
    }
  }

  // ---- epilogue: wave-private rows x cols, direct store ----
  #pragma unroll
  for (int r = 0; r < 4; ++r) {
    const float inv = 1.0f / den[r];
    const int orow = rowbase + rowmap[r];
    const int c0 = t0 * 16 + colmap[r];
    const int c1 = t1 * 16 + colmap[r];
    out[(size_t)orow * FOUT + c0] = acc0[r] * inv + bias[c0];
    out[(size_t)orow * FOUT + c1] = acc1[r] * inv + bias[c1];
  }
}

// ---------------------------------------------------------------------------
extern "C" void kernel_launch(void* const* d_in, const int* in_sizes, int n_in,
                              void* d_out, int out_size, void* d_ws, size_t ws_size,
                              hipStream_t stream) {
  const float* x    = (const float*)d_in[0];
  const int*   adj  = (const int*)d_in[1];
  const float* W    = (const float*)d_in[2];
  const float* a1   = (const float*)d_in[3];
  const float* a2   = (const float*)d_in[4];
  const float* bias = (const float*)d_in[5];
  float* out = (float*)d_out;

  char* ws = (char*)d_ws;
  unsigned short* ht = (unsigned short*)ws;                            // 2 MB
  float* Etab = (float*)(ws + (size_t)2 * 1024 * 1024);                // 64 KB
  unsigned short* FbfF =
      (unsigned short*)(ws + (size_t)2 * 1024 * 1024 + 64 * 1024);     // 16 KB
  unsigned short* FbfF2 = FbfF + NN;                                   // 16 KB

  k_hw<<<NN / 8, 256, 0, stream>>>(x, W, a1, a2, ht, Etab, FbfF, FbfF2);
  k_gat<<<NN / 16, 256, 0, stream>>>(adj, ht, Etab, FbfF, FbfF2, bias, out);
}